// Round 7
// baseline (114.632 us; speedup 1.0000x reference)
//
#include <hip/hip_runtime.h>
#include <hip/hip_bf16.h>
#include <math.h>

#define B_ROWS 4096
#define N_ROWS 8192
#define D 128
#define EXP2_SCALE 2.8853900817779268f  // 2/T*log2(e): exp(sim*2) = exp2(sim*EXP2_SCALE)
#define LN2F 0.6931471805599453f
#define NT 64            // 64 row-tiles of 128
#define NBLK 2080        // NT*(NT+1)/2 upper-triangular tile pairs
#define NSLOT 128        // contribution slots per row (64 tiles x 2 waves)

typedef __attribute__((ext_vector_type(8))) short bf16x8;
typedef __attribute__((ext_vector_type(4))) float f32x4;

// ---------------- Kernel 1: L2-normalize rows -> bf16 Zu (unit) and Zs (x2.885) --
__global__ __launch_bounds__(256) void normalize_kernel(
    const float* __restrict__ z_i, const float* __restrict__ z_j,
    ushort* __restrict__ Zu, ushort* __restrict__ Zs) {
  const int wave = threadIdx.x >> 6;
  const int lane = threadIdx.x & 63;
  const int row = blockIdx.x * 4 + wave;
  const float* src = (row < B_ROWS) ? (z_i + (size_t)row * D)
                                    : (z_j + (size_t)(row - B_ROWS) * D);
  float2 v = *(const float2*)(src + lane * 2);
  float ss = v.x * v.x + v.y * v.y;
#pragma unroll
  for (int off = 32; off > 0; off >>= 1) ss += __shfl_xor(ss, off);
  float scale = 1.0f / fmaxf(sqrtf(ss), 1e-12f);
  float u0 = v.x * scale, u1 = v.y * scale;
  __hip_bfloat16 h0 = __float2bfloat16(u0);
  __hip_bfloat16 h1 = __float2bfloat16(u1);
  __hip_bfloat16 g0 = __float2bfloat16(u0 * EXP2_SCALE);
  __hip_bfloat16 g1 = __float2bfloat16(u1 * EXP2_SCALE);
  ushort2 ou, os;
  ou.x = *(ushort*)&h0; ou.y = *(ushort*)&h1;
  os.x = *(ushort*)&g0; os.y = *(ushort*)&g1;
  *(ushort2*)(Zu + (size_t)row * D + lane * 2) = ou;
  *(ushort2*)(Zs + (size_t)row * D + lane * 2) = os;
}

// ---------------- Kernel 2: symmetric MFMA exp2-rowsum, NO LDS, NO barriers ------
// One block per tile-pair (I,J), J>=I; 4 independent waves (wy,wx), each a 64x64
// subtile. A fragments from Zu (unit rows), B from Zs (rows x 2.885) => MFMA
// output c = log2-units logits directly; epilogue = exp2 + 2 adds, no mul.
// Fragments straight from global: Z* are 2 MB each (L2-resident) and each bf16x8
// load is 100% line-efficient (64 lanes read 16 rows x one full 64B line).
// KEY FIX vs r5 (VGPR=64 + 37MB scratch spills): amdgpu_waves_per_eu(4,4) pins
// the allocator to the 128-reg / 4-waves-per-SIMD tier; live set ~120 fits.
// => 16 waves/CU, zero barriers, VALU (exp2 epilogue) stays fed.
// Partials slots: stripe I row-sums from (I,J) at slot 2J+wx; col-sums from (K,I)
// at slot 2K+wy => 128 slots/row, each written exactly once. No atomics.
__global__ __launch_bounds__(256)
__attribute__((amdgpu_waves_per_eu(4, 4))) void sim_kernel(
    const ushort* __restrict__ Zu, const ushort* __restrict__ Zs,
    float* __restrict__ partials, float* __restrict__ pos_buf) {
  // XCD-aware bijective swizzle (NBLK % 8 == 0)
  int idx = (int)(blockIdx.x % 8) * (NBLK / 8) + (int)(blockIdx.x / 8);
  // decode upper-triangular pair: base(I) = I*NT - I*(I-1)/2
  int I = (int)(64.5f - sqrtf(64.5f * 64.5f - 2.0f * (float)idx));
  if (I < 0) I = 0;
  if (I > NT - 1) I = NT - 1;
  while ((I + 1) * NT - ((I + 1) * I) / 2 <= idx) ++I;
  while (I * NT - (I * (I - 1)) / 2 > idx) --I;
  const int J = I + (idx - (I * NT - (I * (I - 1)) / 2));
  const int rI = I * 128, rJ = J * 128;
  const bool DIAG = (I == J);
  const bool POS = (J == I + 32);  // gi^gj == B_ROWS happens only here

  const int t = threadIdx.x;
  const int lane = t & 63;
  const int w = t >> 6;
  const int wy = w >> 1, wx = w & 1;
  const int l15 = lane & 15;
  const int l4 = lane >> 4;  // 0..3

  // A fragments: wave's 64 rows x K=128 from Zu, resident for the block (64 VGPR).
  bf16x8 a[4][4];  // [row-subtile][k-subtile]
  const int arow = rI + wy * 64 + l15;
#pragma unroll
  for (int rs = 0; rs < 4; ++rs)
#pragma unroll
    for (int ks = 0; ks < 4; ++ks)
      a[rs][ks] = *(const bf16x8*)(Zu + (size_t)(arow + rs * 16) * D + ks * 32 + l4 * 8);

  float rowsum[4][4];
#pragma unroll
  for (int rs = 0; rs < 4; ++rs)
#pragma unroll
    for (int r = 0; r < 4; ++r) rowsum[rs][r] = 0.f;

#pragma unroll
  for (int cs = 0; cs < 4; ++cs) {
    // B fragments for this 16-col subtile (4 K-subtiles) from Zs, straight from L2.
    bf16x8 b[4];
    const int bcol = rJ + wx * 64 + cs * 16 + l15;
#pragma unroll
    for (int ks = 0; ks < 4; ++ks)
      b[ks] = *(const bf16x8*)(Zs + (size_t)bcol * D + ks * 32 + l4 * 8);

    const int bt = wx * 64 + cs * 16 + l15;  // tile-local col of this lane
    float cp = 0.f;
    // ONE c fragment live at a time: epilogue immediately after each rs.
#pragma unroll
    for (int rs = 0; rs < 4; ++rs) {
      f32x4 c = (f32x4){0.f, 0.f, 0.f, 0.f};
#pragma unroll
      for (int ks = 0; ks < 4; ++ks)
        c = __builtin_amdgcn_mfma_f32_16x16x32_bf16(a[rs][ks], b[ks], c, 0, 0, 0);

      if (!DIAG && !POS) {
        // hot path (2016/2080 blocks): bare exp2 + 2 adds per element
#pragma unroll
        for (int r = 0; r < 4; ++r) {
          float e = __builtin_amdgcn_exp2f(c[r]);
          rowsum[rs][r] += e;
          cp += e;
        }
      } else if (DIAG) {
#pragma unroll
        for (int r = 0; r < 4; ++r) {
          const int at = wy * 64 + rs * 16 + l4 * 4 + r;
          float e = __builtin_amdgcn_exp2f(c[r]);
          rowsum[rs][r] += (at != bt) ? e : 0.f;  // exact diagonal mask
          // diagonal tile contributes row-sums only (computed in full)
        }
      } else {  // POS tile (J == I+32): tile diagonal holds the positive pairs
#pragma unroll
        for (int r = 0; r < 4; ++r) {
          const int at = wy * 64 + rs * 16 + l4 * 4 + r;
          float e = __builtin_amdgcn_exp2f(c[r]);
          if (at == bt) {
            pos_buf[rI + at] = c[r];  // positive logit, log2 units (x ln2 later)
            pos_buf[rJ + at] = c[r];  // mirror row (same value by symmetry)
          }
          rowsum[rs][r] += e;
          cp += e;
        }
      }
    }

    // Col sums for this cs (symmetry credit to J rows): reduce across the
    // 4 row-lane-groups; lanes 0..15 store 16 contiguous floats (64B line).
    if (!DIAG) {
      float v = cp;
      v += __shfl_xor(v, 16);
      v += __shfl_xor(v, 32);
      if (l4 == 0)
        partials[(size_t)(2 * I + wy) * N_ROWS + rJ + wx * 64 + cs * 16 + l15] = v;
    }
  }

  // Row sums: butterfly across the 16 column-lanes, then float4 store by the
  // 4 lanes with l15==0 (64B line per rs) to slot 2J+wx.
#pragma unroll
  for (int rs = 0; rs < 4; ++rs) {
    f32x4 v4;
#pragma unroll
    for (int r = 0; r < 4; ++r) {
      float v = rowsum[rs][r];
      v += __shfl_xor(v, 1);
      v += __shfl_xor(v, 2);
      v += __shfl_xor(v, 4);
      v += __shfl_xor(v, 8);
      v4[r] = v;
    }
    if (l15 == 0)
      *(f32x4*)&partials[(size_t)(2 * J + wx) * N_ROWS + rI + wy * 64 + rs * 16 + l4 * 4] = v4;
  }
}

// ---------------- Kernel 3: per-row term + block partial sums ----------------
// Everything is in log2 units: term_ln = (log2(sum) - pos_log2) * ln2.
__global__ __launch_bounds__(256) void reduce1_kernel(
    const float* __restrict__ partials, const float* __restrict__ pos_buf,
    float* __restrict__ loss_part) {
  const int row = blockIdx.x * 256 + threadIdx.x;
  float tot = 0.f;
#pragma unroll 8
  for (int s = 0; s < NSLOT; ++s) tot += partials[(size_t)s * N_ROWS + row];
  float term = (log2f(tot) - pos_buf[row]) * LN2F;
#pragma unroll
  for (int off = 32; off > 0; off >>= 1) term += __shfl_xor(term, off);
  __shared__ float wsum[4];
  if ((threadIdx.x & 63) == 0) wsum[threadIdx.x >> 6] = term;
  __syncthreads();
  if (threadIdx.x == 0)
    loss_part[blockIdx.x] = wsum[0] + wsum[1] + wsum[2] + wsum[3];
}

// ---------------- Kernel 4: final 32 -> 1 ----------------
__global__ __launch_bounds__(64) void reduce2_kernel(
    const float* __restrict__ loss_part, float* __restrict__ out) {
  float v = (threadIdx.x < 32) ? loss_part[threadIdx.x] : 0.f;
#pragma unroll
  for (int off = 32; off > 0; off >>= 1) v += __shfl_xor(v, off);
  if (threadIdx.x == 0) out[0] = v / (float)N_ROWS;
}

extern "C" void kernel_launch(void* const* d_in, const int* in_sizes, int n_in,
                              void* d_out, int out_size, void* d_ws, size_t ws_size,
                              hipStream_t stream) {
  const float* z_i = (const float*)d_in[0];
  const float* z_j = (const float*)d_in[1];
  float* out = (float*)d_out;

  ushort* Zu = (ushort*)d_ws;                                       // 2 MB
  ushort* Zs = Zu + (size_t)N_ROWS * D;                             // 2 MB
  float* partials = (float*)(Zs + (size_t)N_ROWS * D);              // 4 MB
  float* pos_buf = partials + (size_t)NSLOT * N_ROWS;               // 32 KB
  float* loss_part = pos_buf + N_ROWS;                              // small

  hipLaunchKernelGGL(normalize_kernel, dim3(N_ROWS / 4), dim3(256), 0, stream,
                     z_i, z_j, Zu, Zs);
  hipLaunchKernelGGL(sim_kernel, dim3(NBLK), dim3(256), 0, stream, Zu, Zs,
                     partials, pos_buf);
  hipLaunchKernelGGL(reduce1_kernel, dim3(N_ROWS / 256), dim3(256), 0, stream,
                     partials, pos_buf, loss_part);
  hipLaunchKernelGGL(reduce2_kernel, dim3(1), dim3(64), 0, stream, loss_part,
                     out);
}

// Round 9
// 107.281 us; speedup vs baseline: 1.0685x; 1.0685x over previous
//
#include <hip/hip_runtime.h>
#include <hip/hip_bf16.h>
#include <math.h>

#define B_ROWS 4096
#define N_ROWS 8192
#define D 128
#define EXP2_SCALE 2.8853900817779268f  // 2/T*log2(e): exp(sim*2) = exp2(sim*EXP2_SCALE)
#define LN2F 0.6931471805599453f
#define NT 64            // 64 row-tiles of 128
#define NBLK 2080        // NT*(NT+1)/2 upper-triangular tile pairs
#define NSLOT 64         // contribution slots per row (one per tile pair)

typedef __attribute__((ext_vector_type(8))) short bf16x8;
typedef __attribute__((ext_vector_type(4))) float f32x4;

#define MFMA(A, B, C) __builtin_amdgcn_mfma_f32_16x16x32_bf16(A, B, C, 0, 0, 0)

// ---------------- Kernel 1: L2-normalize rows -> bf16 Zu (unit) and Zs (x2.885) --
__global__ __launch_bounds__(256) void normalize_kernel(
    const float* __restrict__ z_i, const float* __restrict__ z_j,
    ushort* __restrict__ Zu, ushort* __restrict__ Zs) {
  const int wave = threadIdx.x >> 6;
  const int lane = threadIdx.x & 63;
  const int row = blockIdx.x * 4 + wave;
  const float* src = (row < B_ROWS) ? (z_i + (size_t)row * D)
                                    : (z_j + (size_t)(row - B_ROWS) * D);
  float2 v = *(const float2*)(src + lane * 2);
  float ss = v.x * v.x + v.y * v.y;
#pragma unroll
  for (int off = 32; off > 0; off >>= 1) ss += __shfl_xor(ss, off);
  float scale = 1.0f / fmaxf(sqrtf(ss), 1e-12f);
  float u0 = v.x * scale, u1 = v.y * scale;
  __hip_bfloat16 h0 = __float2bfloat16(u0);
  __hip_bfloat16 h1 = __float2bfloat16(u1);
  __hip_bfloat16 g0 = __float2bfloat16(u0 * EXP2_SCALE);
  __hip_bfloat16 g1 = __float2bfloat16(u1 * EXP2_SCALE);
  ushort2 ou, os;
  ou.x = *(ushort*)&h0; ou.y = *(ushort*)&h1;
  os.x = *(ushort*)&g0; os.y = *(ushort*)&g1;
  *(ushort2*)(Zu + (size_t)row * D + lane * 2) = ou;
  *(ushort2*)(Zs + (size_t)row * D + lane * 2) = os;
}

// ---------------- Kernel 2: symmetric MFMA exp2-rowsum, 64-VGPR design ----------
// One block per tile-pair (I,J), J>=I. Wave w owns tile rows [w*32,w*32+32) and
// ALL 128 cols. Live set ~60 VGPR (a: 8 named bf16x8 = 32; b: 4 named = 16;
// c0,c1 = 8; rsum = 8) -- fits the allocator's preferred 64-reg/8-wave tier with
// NO spills (r5/r7 showed attributes cannot force a bigger allocation; 37MB of
// scratch traffic was the bottleneck). No arrays anywhere (rule-20-proof).
// Row-sums per wave are complete => ONE slot per tile: stripe I gets row-sums
// from (I,J) at slot J (J>=I) and col-sums from (K,I) at slot K (K<I): all 64
// slots written exactly once. Col-sums combined across waves via 2KB LDS.
__global__ __launch_bounds__(256) void sim_kernel(
    const ushort* __restrict__ Zu, const ushort* __restrict__ Zs,
    float* __restrict__ partials, float* __restrict__ pos_buf) {
  __shared__ float colpart[4][128];  // per-wave col partials (2 KB)

  // XCD-aware bijective swizzle (NBLK % 8 == 0)
  int idx = (int)(blockIdx.x % 8) * (NBLK / 8) + (int)(blockIdx.x / 8);
  // decode upper-triangular pair: base(I) = I*NT - I*(I-1)/2
  int I = (int)(64.5f - sqrtf(64.5f * 64.5f - 2.0f * (float)idx));
  if (I < 0) I = 0;
  if (I > NT - 1) I = NT - 1;
  while ((I + 1) * NT - ((I + 1) * I) / 2 <= idx) ++I;
  while (I * NT - (I * (I - 1)) / 2 > idx) --I;
  const int J = I + (idx - (I * NT - (I * (I - 1)) / 2));
  const int rI = I * 128, rJ = J * 128;
  const bool DIAG = (I == J);
  const bool POS = (J == I + 32);  // gi^gj == B_ROWS happens only here

  const int t = threadIdx.x;
  const int lane = t & 63;
  const int w = t >> 6;
  const int l15 = lane & 15;
  const int l4 = lane >> 4;  // 0..3

  // A fragments: 2 row-subtiles x 4 K-subtiles, named (32 VGPR resident).
  const ushort* Abase = Zu + (size_t)(rI + w * 32 + l15) * D + l4 * 8;
  const bf16x8 a00 = *(const bf16x8*)(Abase);
  const bf16x8 a01 = *(const bf16x8*)(Abase + 32);
  const bf16x8 a02 = *(const bf16x8*)(Abase + 64);
  const bf16x8 a03 = *(const bf16x8*)(Abase + 96);
  const bf16x8 a10 = *(const bf16x8*)(Abase + 16 * D);
  const bf16x8 a11 = *(const bf16x8*)(Abase + 16 * D + 32);
  const bf16x8 a12 = *(const bf16x8*)(Abase + 16 * D + 64);
  const bf16x8 a13 = *(const bf16x8*)(Abase + 16 * D + 96);

  f32x4 rsum0 = {0.f, 0.f, 0.f, 0.f};
  f32x4 rsum1 = {0.f, 0.f, 0.f, 0.f};

#pragma unroll
  for (int cs = 0; cs < 8; ++cs) {
    const ushort* Bbase = Zs + (size_t)(rJ + cs * 16 + l15) * D + l4 * 8;
    bf16x8 b0 = *(const bf16x8*)(Bbase);
    bf16x8 b1 = *(const bf16x8*)(Bbase + 32);
    bf16x8 b2 = *(const bf16x8*)(Bbase + 64);
    bf16x8 b3 = *(const bf16x8*)(Bbase + 96);
    f32x4 c0 = {0.f, 0.f, 0.f, 0.f};
    f32x4 c1 = {0.f, 0.f, 0.f, 0.f};
    c0 = MFMA(a00, b0, c0); c1 = MFMA(a10, b0, c1);
    c0 = MFMA(a01, b1, c0); c1 = MFMA(a11, b1, c1);
    c0 = MFMA(a02, b2, c0); c1 = MFMA(a12, b2, c1);
    c0 = MFMA(a03, b3, c0); c1 = MFMA(a13, b3, c1);

    const int bt = cs * 16 + l15;  // tile-local col of this lane
    float cp = 0.f;
    if (!DIAG && !POS) {
      // hot path (2016/2080 blocks): bare exp2 + adds
#pragma unroll
      for (int r = 0; r < 4; ++r) {
        float e0 = __builtin_amdgcn_exp2f(c0[r]);
        float e1 = __builtin_amdgcn_exp2f(c1[r]);
        rsum0[r] += e0;
        rsum1[r] += e1;
        cp += e0 + e1;
      }
    } else if (DIAG) {
#pragma unroll
      for (int r = 0; r < 4; ++r) {
        const int at0 = w * 32 + l4 * 4 + r;   // rs=0 tile-local row
        const int at1 = at0 + 16;              // rs=1
        float e0 = __builtin_amdgcn_exp2f(c0[r]);
        float e1 = __builtin_amdgcn_exp2f(c1[r]);
        rsum0[r] += (at0 != bt) ? e0 : 0.f;    // exact diagonal mask
        rsum1[r] += (at1 != bt) ? e1 : 0.f;
        // diagonal tile contributes row-sums only (computed in full)
      }
    } else {  // POS tile (J == I+32): tile diagonal holds the positive pairs
#pragma unroll
      for (int r = 0; r < 4; ++r) {
        const int at0 = w * 32 + l4 * 4 + r;
        const int at1 = at0 + 16;
        float e0 = __builtin_amdgcn_exp2f(c0[r]);
        float e1 = __builtin_amdgcn_exp2f(c1[r]);
        if (at0 == bt) { pos_buf[rI + at0] = c0[r]; pos_buf[rJ + at0] = c0[r]; }
        if (at1 == bt) { pos_buf[rI + at1] = c1[r]; pos_buf[rJ + at1] = c1[r]; }
        rsum0[r] += e0;
        rsum1[r] += e1;
        cp += e0 + e1;
      }
    }
    // col partial for this cs: reduce across the 4 row-lane-groups
    cp += __shfl_xor(cp, 16);
    cp += __shfl_xor(cp, 32);
    if (l4 == 0) colpart[w][bt] = cp;
  }

  // Row sums: butterfly across the 16 column-lanes; rows are complete (all cols).
#pragma unroll
  for (int r = 0; r < 4; ++r) {
    float v0 = rsum0[r], v1 = rsum1[r];
    v0 += __shfl_xor(v0, 1); v0 += __shfl_xor(v0, 2);
    v0 += __shfl_xor(v0, 4); v0 += __shfl_xor(v0, 8);
    v1 += __shfl_xor(v1, 1); v1 += __shfl_xor(v1, 2);
    v1 += __shfl_xor(v1, 4); v1 += __shfl_xor(v1, 8);
    rsum0[r] = v0; rsum1[r] = v1;
  }
  if (l15 == 0) {  // 4 lanes (l4=0..3) store 2x contiguous 64B lines
    *(f32x4*)&partials[(size_t)J * N_ROWS + rI + w * 32 + l4 * 4] = rsum0;
    *(f32x4*)&partials[(size_t)J * N_ROWS + rI + w * 32 + 16 + l4 * 4] = rsum1;
  }

  // Col sums (symmetry credit to stripe J): combine 4 wave partials, slot I.
  __syncthreads();
  if (!DIAG && t < 128) {
    float v = colpart[0][t] + colpart[1][t] + colpart[2][t] + colpart[3][t];
    partials[(size_t)I * N_ROWS + rJ + t] = v;
  }
}

// ---------------- Kernel 3: per-row term + block partial sums ----------------
// Everything is in log2 units: term_ln = (log2(sum) - pos_log2) * ln2.
__global__ __launch_bounds__(256) void reduce1_kernel(
    const float* __restrict__ partials, const float* __restrict__ pos_buf,
    float* __restrict__ loss_part) {
  const int row = blockIdx.x * 256 + threadIdx.x;
  float tot = 0.f;
#pragma unroll 8
  for (int s = 0; s < NSLOT; ++s) tot += partials[(size_t)s * N_ROWS + row];
  float term = (log2f(tot) - pos_buf[row]) * LN2F;
#pragma unroll
  for (int off = 32; off > 0; off >>= 1) term += __shfl_xor(term, off);
  __shared__ float wsum[4];
  if ((threadIdx.x & 63) == 0) wsum[threadIdx.x >> 6] = term;
  __syncthreads();
  if (threadIdx.x == 0)
    loss_part[blockIdx.x] = wsum[0] + wsum[1] + wsum[2] + wsum[3];
}

// ---------------- Kernel 4: final 32 -> 1 ----------------
__global__ __launch_bounds__(64) void reduce2_kernel(
    const float* __restrict__ loss_part, float* __restrict__ out) {
  float v = (threadIdx.x < 32) ? loss_part[threadIdx.x] : 0.f;
#pragma unroll
  for (int off = 32; off > 0; off >>= 1) v += __shfl_xor(v, off);
  if (threadIdx.x == 0) out[0] = v / (float)N_ROWS;
}

extern "C" void kernel_launch(void* const* d_in, const int* in_sizes, int n_in,
                              void* d_out, int out_size, void* d_ws, size_t ws_size,
                              hipStream_t stream) {
  const float* z_i = (const float*)d_in[0];
  const float* z_j = (const float*)d_in[1];
  float* out = (float*)d_out;

  ushort* Zu = (ushort*)d_ws;                                       // 2 MB
  ushort* Zs = Zu + (size_t)N_ROWS * D;                             // 2 MB
  float* partials = (float*)(Zs + (size_t)N_ROWS * D);              // 2 MB
  float* pos_buf = partials + (size_t)NSLOT * N_ROWS;               // 32 KB
  float* loss_part = pos_buf + N_ROWS;                              // small

  hipLaunchKernelGGL(normalize_kernel, dim3(N_ROWS / 4), dim3(256), 0, stream,
                     z_i, z_j, Zu, Zs);
  hipLaunchKernelGGL(sim_kernel, dim3(NBLK), dim3(256), 0, stream, Zu, Zs,
                     partials, pos_buf);
  hipLaunchKernelGGL(reduce1_kernel, dim3(N_ROWS / 256), dim3(256), 0, stream,
                     partials, pos_buf, loss_part);
  hipLaunchKernelGGL(reduce2_kernel, dim3(1), dim3(64), 0, stream, loss_part,
                     out);
}

// Round 10
// 83.363 us; speedup vs baseline: 1.3751x; 1.2869x over previous
//
#include <hip/hip_runtime.h>
#include <hip/hip_bf16.h>
#include <math.h>

#define B_ROWS 4096
#define N_ROWS 8192
#define D 128
#define EXP2_SCALE 2.8853900817779268f  // 2/T*log2(e): exp(sim*2) = exp2(sim*EXP2_SCALE)
#define LN2F 0.6931471805599453f
#define NT 32            // 32 row-tiles of 256
#define NBLK 528         // NT*(NT+1)/2 upper-triangular tile pairs (528%8==0)
#define NSLOT 32         // contribution slots per row (one per tile pair)
#define TS 256           // tile size

#define AS1 __attribute__((address_space(1)))
#define AS3 __attribute__((address_space(3)))

typedef __attribute__((ext_vector_type(8))) short bf16x8;
typedef __attribute__((ext_vector_type(4))) float f32x4;

#define MFMA(A, B, C) __builtin_amdgcn_mfma_f32_16x16x32_bf16(A, B, C, 0, 0, 0)

// ---------------- Kernel 1: L2-normalize rows -> bf16 Zu (unit) and Zs (x2.885) --
__global__ __launch_bounds__(256) void normalize_kernel(
    const float* __restrict__ z_i, const float* __restrict__ z_j,
    ushort* __restrict__ Zu, ushort* __restrict__ Zs) {
  const int wave = threadIdx.x >> 6;
  const int lane = threadIdx.x & 63;
  const int row = blockIdx.x * 4 + wave;
  const float* src = (row < B_ROWS) ? (z_i + (size_t)row * D)
                                    : (z_j + (size_t)(row - B_ROWS) * D);
  float2 v = *(const float2*)(src + lane * 2);
  float ss = v.x * v.x + v.y * v.y;
#pragma unroll
  for (int off = 32; off > 0; off >>= 1) ss += __shfl_xor(ss, off);
  float scale = 1.0f / fmaxf(sqrtf(ss), 1e-12f);
  float u0 = v.x * scale, u1 = v.y * scale;
  __hip_bfloat16 h0 = __float2bfloat16(u0);
  __hip_bfloat16 h1 = __float2bfloat16(u1);
  __hip_bfloat16 g0 = __float2bfloat16(u0 * EXP2_SCALE);
  __hip_bfloat16 g1 = __float2bfloat16(u1 * EXP2_SCALE);
  ushort2 ou, os;
  ou.x = *(ushort*)&h0; ou.y = *(ushort*)&h1;
  os.x = *(ushort*)&g0; os.y = *(ushort*)&g1;
  *(ushort2*)(Zu + (size_t)row * D + lane * 2) = ou;
  *(ushort2*)(Zs + (size_t)row * D + lane * 2) = os;
}

// ---------------- Kernel 2: symmetric MFMA exp2-rowsum, 256x256 tiles ----------
// r9 falsified spills-as-bottleneck: spill-free 48-VGPR version was still 49us
// with all pipes <15%. Invariant across 5 structures: ~300MB of L2 fragment
// traffic at ~6.8 TB/s effective => L2 transaction-rate bound. Fix: cut L2
// bytes 5x with 256x256 tile pairs (NBLK=528): A read direct (no redundancy,
// 64KB/block), B staged ONCE to LDS (64KB/block) and reused by all 8 waves.
// Staging uses global_load_lds (zero staging VGPRs): linear LDS dest +
// pre-XOR'd per-lane source; reads apply the same XOR ((row&7)<<4) =>
// bank-conflict-free ds_read_b128 (0 conflicts measured in r3/r6).
// Wave w owns tile rows [w*32,w*32+32) and ALL 256 cols => per-wave row-sums
// are complete: ONE partials slot per tile pair. Stripe I gets row-sums from
// (I,J) at slot J and col-sums from (K,I) at slot K => 32 slots, each exactly
// once. Col-sums combined across the 8 waves via 8KB LDS. No atomics.
__global__ __launch_bounds__(512) void sim_kernel(
    const ushort* __restrict__ Zu, const ushort* __restrict__ Zs,
    float* __restrict__ partials, float* __restrict__ pos_buf) {
  __shared__ ushort ldsB[TS * 128];     // 64 KB, stripe J (swizzled content)
  __shared__ float colpart[8][TS];      // 8 KB per-wave col partials

  // XCD-aware bijective swizzle (NBLK % 8 == 0)
  int idx = (int)(blockIdx.x % 8) * (NBLK / 8) + (int)(blockIdx.x / 8);
  // decode upper-triangular pair: base(I) = I*NT - I*(I-1)/2
  int I = (int)(32.5f - sqrtf(32.5f * 32.5f - 2.0f * (float)idx));
  if (I < 0) I = 0;
  if (I > NT - 1) I = NT - 1;
  while ((I + 1) * NT - ((I + 1) * I) / 2 <= idx) ++I;
  while (I * NT - (I * (I - 1)) / 2 > idx) --I;
  const int J = I + (idx - (I * NT - (I * (I - 1)) / 2));
  const int rI = I * TS, rJ = J * TS;
  const bool DIAG = (I == J);
  const bool POS = (J == I + 16);  // gi^gj == B_ROWS: 4096/256 = 16 tiles apart

  const int t = threadIdx.x;
  const int lane = t & 63;
  const int w = t >> 6;      // 0..7
  const int l15 = lane & 15;
  const int l4 = lane >> 4;  // 0..3

  // ---- Issue A loads FIRST (latency hides under B staging + barrier) ----
  // Wave w owns stripe-I rows [w*32, w*32+32): 2 row-subtiles x 4 K-subtiles.
  const ushort* Abase = Zu + (size_t)(rI + w * 32 + l15) * D + l4 * 8;
  const bf16x8 a00 = *(const bf16x8*)(Abase);
  const bf16x8 a01 = *(const bf16x8*)(Abase + 32);
  const bf16x8 a02 = *(const bf16x8*)(Abase + 64);
  const bf16x8 a03 = *(const bf16x8*)(Abase + 96);
  const bf16x8 a10 = *(const bf16x8*)(Abase + 16 * D);
  const bf16x8 a11 = *(const bf16x8*)(Abase + 16 * D + 32);
  const bf16x8 a12 = *(const bf16x8*)(Abase + 16 * D + 64);
  const bf16x8 a13 = *(const bf16x8*)(Abase + 16 * D + 96);

  // ---- Stage stripe J into LDS: 8 rounds x (8 waves x 1KB) ----
  // Linear wave-uniform dest; source pre-XOR'd so LDS[row][x] = Z[row][x^sw].
  {
    const int rsub = lane >> 4;  // 0..3 row within this wave's 4-row group
#pragma unroll
    for (int i = 0; i < 8; ++i) {
      const int row = i * 32 + w * 4 + rsub;               // 0..255
      const int srcoff = ((lane & 15) * 16) ^ ((row & 7) << 4);
      const char* src = (const char*)Zs + (size_t)(rJ + row) * 256 + srcoff;
      char* dst = (char*)ldsB + (size_t)(i * 32 + w * 4) * 256;  // uniform/wave
      __builtin_amdgcn_global_load_lds((AS1 const unsigned int*)src,
                                       (AS3 unsigned int*)dst, 16, 0, 0);
    }
  }
  __syncthreads();  // vmcnt(0) drain before use

  f32x4 rsum0 = {0.f, 0.f, 0.f, 0.f};
  f32x4 rsum1 = {0.f, 0.f, 0.f, 0.f};

#pragma unroll 4
  for (int cs = 0; cs < 16; ++cs) {
    // B fragments for cols [cs*16, cs*16+16) from LDS (swizzled read).
    const int br = cs * 16 + l15;
    const int bo = br * 256, bsw = (br & 7) << 4;
    bf16x8 b0 = *(const bf16x8*)((const char*)ldsB + bo + ((0 + l4 * 16) ^ bsw));
    bf16x8 b1 = *(const bf16x8*)((const char*)ldsB + bo + ((64 + l4 * 16) ^ bsw));
    bf16x8 b2 = *(const bf16x8*)((const char*)ldsB + bo + ((128 + l4 * 16) ^ bsw));
    bf16x8 b3 = *(const bf16x8*)((const char*)ldsB + bo + ((192 + l4 * 16) ^ bsw));
    f32x4 c0 = {0.f, 0.f, 0.f, 0.f};
    f32x4 c1 = {0.f, 0.f, 0.f, 0.f};
    c0 = MFMA(a00, b0, c0); c1 = MFMA(a10, b0, c1);
    c0 = MFMA(a01, b1, c0); c1 = MFMA(a11, b1, c1);
    c0 = MFMA(a02, b2, c0); c1 = MFMA(a12, b2, c1);
    c0 = MFMA(a03, b3, c0); c1 = MFMA(a13, b3, c1);

    const int bt = cs * 16 + l15;  // tile-local col of this lane
    float cp = 0.f;
    if (!DIAG && !POS) {
      // hot path (480/528 blocks): bare exp2 + adds
#pragma unroll
      for (int r = 0; r < 4; ++r) {
        float e0 = __builtin_amdgcn_exp2f(c0[r]);
        float e1 = __builtin_amdgcn_exp2f(c1[r]);
        rsum0[r] += e0;
        rsum1[r] += e1;
        cp += e0 + e1;
      }
    } else if (DIAG) {
#pragma unroll
      for (int r = 0; r < 4; ++r) {
        const int at0 = w * 32 + l4 * 4 + r;   // tile-local row (c0)
        const int at1 = at0 + 16;              // (c1)
        float e0 = __builtin_amdgcn_exp2f(c0[r]);
        float e1 = __builtin_amdgcn_exp2f(c1[r]);
        rsum0[r] += (at0 != bt) ? e0 : 0.f;    // exact diagonal mask
        rsum1[r] += (at1 != bt) ? e1 : 0.f;
        // diagonal tile contributes row-sums only (computed in full)
      }
    } else {  // POS tile (J == I+16): tile diagonal holds the positive pairs
#pragma unroll
      for (int r = 0; r < 4; ++r) {
        const int at0 = w * 32 + l4 * 4 + r;
        const int at1 = at0 + 16;
        float e0 = __builtin_amdgcn_exp2f(c0[r]);
        float e1 = __builtin_amdgcn_exp2f(c1[r]);
        if (at0 == bt) { pos_buf[rI + at0] = c0[r]; pos_buf[rJ + at0] = c0[r]; }
        if (at1 == bt) { pos_buf[rI + at1] = c1[r]; pos_buf[rJ + at1] = c1[r]; }
        rsum0[r] += e0;
        rsum1[r] += e1;
        cp += e0 + e1;
      }
    }
    // col partial for this cs: reduce across the 4 row-lane-groups
    cp += __shfl_xor(cp, 16);
    cp += __shfl_xor(cp, 32);
    if (l4 == 0) colpart[w][bt] = cp;
  }

  // Row sums: butterfly across the 16 column-lanes; rows complete (all 256 cols).
#pragma unroll
  for (int r = 0; r < 4; ++r) {
    float v0 = rsum0[r], v1 = rsum1[r];
    v0 += __shfl_xor(v0, 1); v0 += __shfl_xor(v0, 2);
    v0 += __shfl_xor(v0, 4); v0 += __shfl_xor(v0, 8);
    v1 += __shfl_xor(v1, 1); v1 += __shfl_xor(v1, 2);
    v1 += __shfl_xor(v1, 4); v1 += __shfl_xor(v1, 8);
    rsum0[r] = v0; rsum1[r] = v1;
  }
  if (l15 == 0) {  // 4 lanes (l4=0..3) store 2x contiguous 64B lines
    *(f32x4*)&partials[(size_t)J * N_ROWS + rI + w * 32 + l4 * 4] = rsum0;
    *(f32x4*)&partials[(size_t)J * N_ROWS + rI + w * 32 + 16 + l4 * 4] = rsum1;
  }

  // Col sums (symmetry credit to stripe J): combine 8 wave partials, slot I.
  __syncthreads();
  if (!DIAG && t < TS) {
    float v = colpart[0][t] + colpart[1][t] + colpart[2][t] + colpart[3][t] +
              colpart[4][t] + colpart[5][t] + colpart[6][t] + colpart[7][t];
    partials[(size_t)I * N_ROWS + rJ + t] = v;
  }
}

// ---------------- Kernel 3: per-row term + block partial sums ----------------
// Everything is in log2 units: term_ln = (log2(sum) - pos_log2) * ln2.
__global__ __launch_bounds__(256) void reduce1_kernel(
    const float* __restrict__ partials, const float* __restrict__ pos_buf,
    float* __restrict__ loss_part) {
  const int row = blockIdx.x * 256 + threadIdx.x;
  float tot = 0.f;
#pragma unroll 8
  for (int s = 0; s < NSLOT; ++s) tot += partials[(size_t)s * N_ROWS + row];
  float term = (log2f(tot) - pos_buf[row]) * LN2F;
#pragma unroll
  for (int off = 32; off > 0; off >>= 1) term += __shfl_xor(term, off);
  __shared__ float wsum[4];
  if ((threadIdx.x & 63) == 0) wsum[threadIdx.x >> 6] = term;
  __syncthreads();
  if (threadIdx.x == 0)
    loss_part[blockIdx.x] = wsum[0] + wsum[1] + wsum[2] + wsum[3];
}

// ---------------- Kernel 4: final 32 -> 1 ----------------
__global__ __launch_bounds__(64) void reduce2_kernel(
    const float* __restrict__ loss_part, float* __restrict__ out) {
  float v = (threadIdx.x < 32) ? loss_part[threadIdx.x] : 0.f;
#pragma unroll
  for (int off = 32; off > 0; off >>= 1) v += __shfl_xor(v, off);
  if (threadIdx.x == 0) out[0] = v / (float)N_ROWS;
}

extern "C" void kernel_launch(void* const* d_in, const int* in_sizes, int n_in,
                              void* d_out, int out_size, void* d_ws, size_t ws_size,
                              hipStream_t stream) {
  const float* z_i = (const float*)d_in[0];
  const float* z_j = (const float*)d_in[1];
  float* out = (float*)d_out;

  ushort* Zu = (ushort*)d_ws;                                       // 2 MB
  ushort* Zs = Zu + (size_t)N_ROWS * D;                             // 2 MB
  float* partials = (float*)(Zs + (size_t)N_ROWS * D);              // 1 MB
  float* pos_buf = partials + (size_t)NSLOT * N_ROWS;               // 32 KB
  float* loss_part = pos_buf + N_ROWS;                              // small

  hipLaunchKernelGGL(normalize_kernel, dim3(N_ROWS / 4), dim3(256), 0, stream,
                     z_i, z_j, Zu, Zs);
  hipLaunchKernelGGL(sim_kernel, dim3(NBLK), dim3(512), 0, stream, Zu, Zs,
                     partials, pos_buf);
  hipLaunchKernelGGL(reduce1_kernel, dim3(N_ROWS / 256), dim3(256), 0, stream,
                     partials, pos_buf, loss_part);
  hipLaunchKernelGGL(reduce2_kernel, dim3(1), dim3(64), 0, stream, loss_part,
                     out);
}